// Round 10
// baseline (50.995 us; speedup 1.0000x reference)
//
#include <hip/hip_runtime.h>

#define TPB 512
#define PPB 8              // planes per block; grid = 4096/PPB = 512 = exactly 2 blocks/CU
#define T1S 132            // t1 float pitch (==4 mod 32, conflict-minimal; rows T=0..71)
#define T2S 72             // t2 u32 pitch (=144 u16 bf16; mult of 4 -> aligned b128 reads)

typedef float v2f __attribute__((ext_vector_type(2)));

// RNE f32->bf16 pair pack (pure ALU, no asm)
__device__ __forceinline__ unsigned int bf2(float a, float b) {
    unsigned int ua = __float_as_uint(a), ub = __float_as_uint(b);
    ua = (ua + 0x7FFFu + ((ua >> 16) & 1u)) >> 16;
    ub = (ub + 0x7FFFu + ((ub >> 16) & 1u)) & 0xFFFF0000u;
    return ua | ub;
}

__global__ __launch_bounds__(TPB, 4)
void afa_fused(const float* __restrict__ in, const float* __restrict__ bias,
               const float* __restrict__ upf, const float* __restrict__ dnf,
               float* __restrict__ out)
{
    __shared__ __align__(16) float        s_t1[72 * T1S];   // 38016 B, W-upsampled rows
    __shared__ __align__(16) unsigned int s_t2[64 * T2S];   // 18432 B, H-downsampled rows (bf16 pairs)

    const int tid = threadIdx.x;
    const int ri = tid >> 3, cb = tid & 7;     // A-stage mapping (row, 8-col group)
    const int c  = tid & 63, q = tid >> 6;     // fusedV mapping (col-pair, 8-row group)

    // taps: filt[0]=filt[11]=0 -> 5-tap up phases, 10-tap down
    float gA[5], gB[5], fhx[5], fhy[5], fd[11];
#pragma unroll
    for (int k = 0; k < 5; ++k) {
        gA[k]  = 2.0f * upf[9 - 2*k];
        gB[k]  = 2.0f * upf[10 - 2*k];
        fhx[k] = 1.41421356237309515f * dnf[2*k + 1];   // H-down odd taps * sqrt2 (lrelu scale folded)
        fhy[k] = 1.41421356237309515f * dnf[2*k + 2];   // H-down even taps * sqrt2
    }
#pragma unroll
    for (int k = 1; k <= 10; ++k) fd[k] = dnf[k];       // W-down taps (unscaled)

    // one-time zeros: t1 pad rows 0..3 / 68..71 (vertical zero-pad), t2 halo cols
    if (tid < 264) {
        *(float2*)(s_t1 + 2 * tid) = make_float2(0.f, 0.f);
        *(float2*)(s_t1 + 68 * T1S + 2 * tid) = make_float2(0.f, 0.f);
    }
    if (tid < 256) {
        const int rw = tid >> 2, k = tid & 3;
        s_t2[rw * T2S + ((k < 2) ? k : 64 + k)] = 0u;   // u32 {0,1,66,67} = cols -4..-1,128..131
    }

    const int plane0 = blockIdx.x * PPB;

    // prefetch plane0 input into registers
    const float4* px = (const float4*)(in + (size_t)plane0 * 4096 + ri * 64);
    float4 x0 = px[cb == 0 ? 0 : 2 * cb - 1];
    float4 x1 = px[2 * cb];
    float4 x2 = px[2 * cb + 1];
    float4 x3 = px[cb == 7 ? 15 : 2 * cb + 2];

    // Wdown body as lambda: t2(bf16) -> global, 2 units/thread
    auto wdown = [&](float* op) {
#pragma unroll
        for (int s_ = 0; s_ < 2; ++s_) {
            const int u = tid + TPB * s_;
            const int oy = u >> 4, oxb = u & 15;
            const unsigned int* b = s_t2 + oy * T2S + 4 * oxb;   // u16 window c=8oxb-4..+11
            const uint4 wA = *(const uint4*)(b);
            const uint4 wB = *(const uint4*)(b + 4);
            float wv[16];
            {
                const unsigned int ws[8] = {wA.x, wA.y, wA.z, wA.w, wB.x, wB.y, wB.z, wB.w};
#pragma unroll
                for (int k = 0; k < 8; ++k) {
                    wv[2*k]   = __uint_as_float(ws[k] << 16);
                    wv[2*k+1] = __uint_as_float(ws[k] & 0xFFFF0000u);
                }
            }
            float o2[4];
#pragma unroll
            for (int p2 = 0; p2 < 4; ++p2) {
                float a2 = 0.f;
#pragma unroll
                for (int k = 0; k < 10; ++k)
                    a2 = fmaf(wv[2*p2 + k], fd[10 - k], a2);
                o2[p2] = a2;
            }
            *(float4*)(op + oy * 64 + 4 * oxb) = make_float4(o2[0], o2[1], o2[2], o2[3]);
        }
    };

    for (int p = 0; p < PPB; ++p) {
        const int plane = plane0 + p;
        const float bv = bias[plane & 511];

        // ---- phase 1: Wdown(plane-1)  ||  A(plane) from prefetched regs  ||  prefetch(plane+1)
        if (p > 0)
            wdown(out + (size_t)(plane - 1) * 4096);

        {
            const float4 z4 = make_float4(0.f, 0.f, 0.f, 0.f);
            const float4 q0 = (cb == 0) ? z4 : x0;
            const float4 q3 = (cb == 7) ? z4 : x3;
            const float xr[12] = {q0.z, q0.w, x1.x, x1.y, x1.z, x1.w,
                                  x2.x, x2.y, x2.z, x2.w, q3.x, q3.y};  // x[8cb-2..8cb+9]
            float* dst = s_t1 + (ri + 4) * T1S + 16 * cb;
#pragma unroll
            for (int h = 0; h < 4; ++h) {
                const int qq = 2 * h;
                float o0 = xr[qq] * gA[0],     o1 = xr[qq] * gB[0];
                float o2_ = xr[qq + 1] * gA[0], o3 = xr[qq + 1] * gB[0];
#pragma unroll
                for (int k = 1; k < 5; ++k) {
                    o0  = fmaf(xr[qq + k],     gA[k], o0);
                    o1  = fmaf(xr[qq + k],     gB[k], o1);
                    o2_ = fmaf(xr[qq + 1 + k], gA[k], o2_);
                    o3  = fmaf(xr[qq + 1 + k], gB[k], o3);
                }
                *(float4*)(dst + 4 * h) = make_float4(o0, o1, o2_, o3);
            }
        }
        if (p + 1 < PPB) {
            const float4* pn = (const float4*)(in + (size_t)(plane + 1) * 4096 + ri * 64);
            x0 = pn[cb == 0 ? 0 : 2 * cb - 1];
            x1 = pn[2 * cb];
            x2 = pn[2 * cb + 1];
            x3 = pn[cb == 7 ? 15 : 2 * cb + 2];
        }
        __syncthreads();

        // ---- phase 2: fusedV (H-up + bias + lrelu + H-down in regs) -> t2 bf16
        {
            v2f cc[16];
#pragma unroll
            for (int t = 0; t < 16; ++t)
                cc[t] = *(const v2f*)(s_t1 + (8 * q + t) * T1S + 2 * c);
            float accx[8] = {0.f,0.f,0.f,0.f,0.f,0.f,0.f,0.f};
            float accy[8] = {0.f,0.f,0.f,0.f,0.f,0.f,0.f,0.f};
            const bool mlo = (q == 0), mhi = (q == 7);
#pragma unroll
            for (int t = 0; t < 12; ++t) {
                float tax = fmaf(cc[t].x, gA[0], bv);
                float tay = fmaf(cc[t].y, gA[0], bv);
                float tbx = fmaf(cc[t].x, gB[0], bv);
                float tby = fmaf(cc[t].y, gB[0], bv);
#pragma unroll
                for (int k = 1; k < 5; ++k) {
                    tax = fmaf(cc[t + k].x, gA[k], tax);
                    tay = fmaf(cc[t + k].y, gA[k], tay);
                    tbx = fmaf(cc[t + k].x, gB[k], tbx);
                    tby = fmaf(cc[t + k].y, gB[k], tby);
                }
                if (mlo && t < 2)   { tax = 0.f; tay = 0.f; tbx = 0.f; tby = 0.f; }
                if (mhi && t >= 10) { tax = 0.f; tay = 0.f; tbx = 0.f; tby = 0.f; }
                const float rax = fmaxf(tax, 0.2f * tax);
                const float ray = fmaxf(tay, 0.2f * tay);
                const float rbx = fmaxf(tbx, 0.2f * tbx);
                const float rby = fmaxf(tby, 0.2f * tby);
#pragma unroll
                for (int pp = 0; pp < 8; ++pp) {
                    if (pp <= t && t <= pp + 4) {
                        const int m = 4 - (t - pp);
                        accx[pp] = fmaf(rax, fhy[m], fmaf(rbx, fhx[m], accx[pp]));
                        accy[pp] = fmaf(ray, fhy[m], fmaf(rby, fhx[m], accy[pp]));
                    }
                }
            }
#pragma unroll
            for (int pp = 0; pp < 8; ++pp)
                s_t2[(8 * q + pp) * T2S + 2 + c] = bf2(accx[pp], accy[pp]);
        }
        __syncthreads();
    }

    // ---- final Wdown for the last plane
    wdown(out + (size_t)(plane0 + PPB - 1) * 4096);
}

extern "C" void kernel_launch(void* const* d_in, const int* in_sizes, int n_in,
                              void* d_out, int out_size, void* d_ws, size_t ws_size,
                              hipStream_t stream) {
    const float* in  = (const float*)d_in[0];
    const float* bv  = (const float*)d_in[1];
    const float* upf = (const float*)d_in[2];
    const float* dnf = (const float*)d_in[3];
    float* out = (float*)d_out;
    afa_fused<<<4096 / PPB, TPB, 0, stream>>>(in, bv, upf, dnf, out);
}

// Round 11
// 47.589 us; speedup vs baseline: 1.0716x; 1.0716x over previous
//
#include <hip/hip_runtime.h>

#define TPB 512
#define H 64
#define W 64

// Both intermediates stored as packed bf16 pairs (u32 = {lo:col even, hi:col odd}).
// P1 ≡ 4 mod 32 (same bank class as the verified 132-float pitch); %4==0 -> b128 aligned.
#define P1 68     // t1: u32[72][68]  (rows T=0..71 <-> input row T-4; rows 0..3/68..71 zero)
#define P2 68     // t2: u32[64][68]  (u32 cols: 0,1 = left halo pairs, 2+cp, 66,67 = right halo)
#define LDS_BYTES ((72 * P1 + 64 * P2) * 4)   // 36992 B -> 4 blocks/CU

__device__ __forceinline__ unsigned int pkbf(float lo, float hi) {
    unsigned int d;
    asm("v_cvt_pk_bf16_f32 %0, %1, %2" : "=v"(d) : "v"(lo), "v"(hi));
    return d;
}
__device__ __forceinline__ float ulo(unsigned int u) { return __uint_as_float(u << 16); }
__device__ __forceinline__ float uhi(unsigned int u) { return __uint_as_float(u & 0xFFFF0000u); }

__global__ __launch_bounds__(TPB, 4)
void afa_fused(const float* __restrict__ in, const float* __restrict__ bias,
               const float* __restrict__ upf, const float* __restrict__ dnf,
               float* __restrict__ out)
{
    __shared__ __align__(16) unsigned int s_t1u[72 * P1];   // 19584 B
    __shared__ __align__(16) unsigned int s_t2u[64 * P2];   // 17408 B

    const int tid = threadIdx.x;
    const int plane = blockIdx.x;            // 4096 blocks, one 64x64 plane each

    // taps: filt[0]=filt[11]=0 -> 5-tap up phases, 10-tap down
    float gA[5], gB[5], fhx[5], fhy[5], fd[11];
#pragma unroll
    for (int k = 0; k < 5; ++k) {
        gA[k]  = 2.0f * upf[9 - 2*k];
        gB[k]  = 2.0f * upf[10 - 2*k];
        fhx[k] = 1.41421356237309515f * dnf[2*k + 1];   // H-down odd taps, lrelu sqrt2 folded
        fhy[k] = 1.41421356237309515f * dnf[2*k + 2];   // H-down even taps
    }
#pragma unroll
    for (int k = 1; k <= 10; ++k) fd[k] = dnf[k];       // W-down taps (unscaled)
    const float bv = bias[plane & 511];

    // one-time zeros: t1 vertical pad rows (0..3, 68..71) and t2 halo cols
    if (tid < 256) {
        const int r = tid >> 6, cc0 = tid & 63;
        s_t1u[r * P1 + cc0] = 0u;
        s_t1u[(68 + r) * P1 + cc0] = 0u;
        const int rw = tid >> 2, k = tid & 3;
        s_t2u[rw * P2 + ((k < 2) ? k : 64 + k)] = 0u;
    }

    // ---- A: global load + horizontal (W) x2 upsample -> t1 (bf16). 512 units = (r, cb).
    {
        const int ri = tid >> 3, cb = tid & 7;
        const float4* p4 = (const float4*)(in + (size_t)plane * (H * W) + ri * W);
        float4 q0 = p4[cb == 0 ? 0 : 2 * cb - 1];
        const float4 q1 = p4[2 * cb];
        const float4 q2 = p4[2 * cb + 1];
        float4 q3 = p4[cb == 7 ? 15 : 2 * cb + 2];
        if (cb == 0) q0 = make_float4(0.f, 0.f, 0.f, 0.f);
        if (cb == 7) q3 = make_float4(0.f, 0.f, 0.f, 0.f);
        const float xr[12] = {q0.z, q0.w, q1.x, q1.y, q1.z, q1.w,
                              q2.x, q2.y, q2.z, q2.w, q3.x, q3.y};   // x[8cb-2 .. 8cb+9]
        float o[16];
#pragma unroll
        for (int q = 0; q < 8; ++q) {
            float e = xr[q] * gA[0];
            float d = xr[q] * gB[0];
#pragma unroll
            for (int k = 1; k < 5; ++k) {
                e = fmaf(xr[q + k], gA[k], e);
                d = fmaf(xr[q + k], gB[k], d);
            }
            o[2*q] = e; o[2*q+1] = d;
        }
        uint4* dst = (uint4*)(s_t1u + (ri + 4) * P1 + 8 * cb);
        dst[0] = make_uint4(pkbf(o[0], o[1]),  pkbf(o[2], o[3]),
                            pkbf(o[4], o[5]),  pkbf(o[6], o[7]));
        dst[1] = make_uint4(pkbf(o[8], o[9]),  pkbf(o[10], o[11]),
                            pkbf(o[12], o[13]), pkbf(o[14], o[15]));
    }
    __syncthreads();

    // ---- fusedV: H-up + bias + lrelu + H-down in registers -> t2 (bf16).
    // 512 units = (col-pair c 0..63, group q 0..7); reads t1 rows 8q..8q+15.
    {
        const int c = tid & 63;
        const int q = tid >> 6;              // wave-uniform
        float ccx[16], ccy[16];
#pragma unroll
        for (int t = 0; t < 16; ++t) {
            const unsigned int u = s_t1u[(8 * q + t) * P1 + c];
            ccx[t] = ulo(u); ccy[t] = uhi(u);
        }
        float accx[8] = {0.f,0.f,0.f,0.f,0.f,0.f,0.f,0.f};
        float accy[8] = {0.f,0.f,0.f,0.f,0.f,0.f,0.f,0.f};
        const bool mlo = (q == 0), mhi = (q == 7);
#pragma unroll
        for (int t = 0; t < 12; ++t) {
            float tax = fmaf(ccx[t], gA[0], bv);
            float tay = fmaf(ccy[t], gA[0], bv);
            float tbx = fmaf(ccx[t], gB[0], bv);
            float tby = fmaf(ccy[t], gB[0], bv);
#pragma unroll
            for (int k = 1; k < 5; ++k) {
                tax = fmaf(ccx[t + k], gA[k], tax);
                tay = fmaf(ccy[t + k], gA[k], tay);
                tbx = fmaf(ccx[t + k], gB[k], tbx);
                tby = fmaf(ccy[t + k], gB[k], tby);
            }
            if (mlo && t < 2)   { tax = 0.f; tay = 0.f; tbx = 0.f; tby = 0.f; }
            if (mhi && t >= 10) { tax = 0.f; tay = 0.f; tbx = 0.f; tby = 0.f; }
            const float rax = fmaxf(tax, 0.2f * tax);
            const float ray = fmaxf(tay, 0.2f * tay);
            const float rbx = fmaxf(tbx, 0.2f * tbx);
            const float rby = fmaxf(tby, 0.2f * tby);
#pragma unroll
            for (int pp = 0; pp < 8; ++pp) {
                if (pp <= t && t <= pp + 4) {
                    const int m = 4 - (t - pp);
                    accx[pp] = fmaf(rax, fhy[m], fmaf(rbx, fhx[m], accx[pp]));
                    accy[pp] = fmaf(ray, fhy[m], fmaf(rby, fhx[m], accy[pp]));
                }
            }
        }
#pragma unroll
        for (int pp = 0; pp < 8; ++pp)
            s_t2u[(8 * q + pp) * P2 + 2 + c] = pkbf(accx[pp], accy[pp]);
    }
    __syncthreads();

    // ---- Wdown: horizontal (W) /2 downsample of t2 (bf16) -> global. 1024 units, 2/thread.
#pragma unroll
    for (int s_ = 0; s_ < 2; ++s_) {
        const int u = tid + TPB * s_;
        const int oy = u >> 4, oxb = u & 15;
        const unsigned int* b = s_t2u + oy * P2 + 4 * oxb;   // u32 idx 4oxb..4oxb+7 = cols 8oxb-4..+11
        const uint4 wA = *(const uint4*)(b);
        const uint4 wB = *(const uint4*)(b + 4);
        const unsigned int ws[8] = {wA.x, wA.y, wA.z, wA.w, wB.x, wB.y, wB.z, wB.w};
        float wv[16];
#pragma unroll
        for (int k = 0; k < 8; ++k) { wv[2*k] = ulo(ws[k]); wv[2*k+1] = uhi(ws[k]); }
        float o2[4];
#pragma unroll
        for (int p2 = 0; p2 < 4; ++p2) {
            float a2 = 0.f;
#pragma unroll
            for (int k = 0; k < 10; ++k)
                a2 = fmaf(wv[2*p2 + k], fd[10 - k], a2);
            o2[p2] = a2;
        }
        float* po = out + (size_t)plane * (H * W) + oy * W + 4 * oxb;
        *(float4*)po = make_float4(o2[0], o2[1], o2[2], o2[3]);
    }
}

extern "C" void kernel_launch(void* const* d_in, const int* in_sizes, int n_in,
                              void* d_out, int out_size, void* d_ws, size_t ws_size,
                              hipStream_t stream) {
    const float* in  = (const float*)d_in[0];
    const float* bv  = (const float*)d_in[1];
    const float* upf = (const float*)d_in[2];
    const float* dnf = (const float*)d_in[3];
    float* out = (float*)d_out;
    afa_fused<<<8 * 512, TPB, 0, stream>>>(in, bv, upf, dnf, out);
}

// Round 12
// 40.435 us; speedup vs baseline: 1.2612x; 1.1769x over previous
//
#include <hip/hip_runtime.h>

#define TPB 512
#define H 64
#define W 64

// t1: W-upsampled rows, T = 0..71 <-> input row r = T-4 (rows 0..3 / 68..71 zero pad)
#define NT1 72
#define T1S 132            // ==4 mod 32: b128 write / b64 col-read at bank minimum
#define T1_FLOATS (NT1 * T1S)   // 9504 floats = 38016 B
// t2: H-downsampled rows (64 x 128 + 4-col halos), ALIASES t1 (acc in regs across barrier)
#define T2S 140
#define T2_OFF 4
#define LDS_FLOATS T1_FLOATS    // 38016 B -> 4 blocks/CU by LDS

typedef float v2f __attribute__((ext_vector_type(2)));

// v_pk_*_f32 packed fp32 (proven on-device in rounds 4-6).
// op_sel[i] = src-i half for LOW result, op_sel_hi[i] = src-i half for HIGH result.
#define PKF_ACC_P(acc,a,b)  asm("v_pk_fma_f32 %0, %1, %2, %0 op_sel:[0,0,0] op_sel_hi:[1,1,1]" : "+v"(acc) : "v"(a), "v"(b))  // plain
#define PKF_ACC_A0(acc,a,b) asm("v_pk_fma_f32 %0, %1, %2, %0 op_sel:[0,0,0] op_sel_hi:[0,1,1]" : "+v"(acc) : "v"(a), "v"(b))  // src0 bcast lo
#define PKF_ACC_A1(acc,a,b) asm("v_pk_fma_f32 %0, %1, %2, %0 op_sel:[1,0,0] op_sel_hi:[1,1,1]" : "+v"(acc) : "v"(a), "v"(b))  // src0 bcast hi
#define PKF_ACC_B0(acc,a,b) asm("v_pk_fma_f32 %0, %1, %2, %0 op_sel:[0,0,0] op_sel_hi:[1,0,1]" : "+v"(acc) : "v"(a), "v"(b))  // src1 bcast lo
#define PKF_ACC_B1(acc,a,b) asm("v_pk_fma_f32 %0, %1, %2, %0 op_sel:[0,1,0] op_sel_hi:[1,1,1]" : "+v"(acc) : "v"(a), "v"(b))  // src1 bcast hi
#define PKF_NEW_B0(d,a,b,c) asm("v_pk_fma_f32 %0, %1, %2, %3 op_sel:[0,0,0] op_sel_hi:[1,0,1]" : "=v"(d) : "v"(a), "v"(b), "v"(c))
#define PKF_NEW_B1(d,a,b,c) asm("v_pk_fma_f32 %0, %1, %2, %3 op_sel:[0,1,0] op_sel_hi:[1,1,1]" : "=v"(d) : "v"(a), "v"(b), "v"(c))
#define PKM_P(d,a,b)        asm("v_pk_mul_f32 %0, %1, %2 op_sel:[0,0] op_sel_hi:[1,1]" : "=v"(d) : "v"(a), "v"(b))            // plain
#define PKM_A0(d,a,b)       asm("v_pk_mul_f32 %0, %1, %2 op_sel:[0,0] op_sel_hi:[0,1]" : "=v"(d) : "v"(a), "v"(b))            // src0 bcast lo
#define PKM_A1(d,a,b)       asm("v_pk_mul_f32 %0, %1, %2 op_sel:[1,0] op_sel_hi:[1,1]" : "=v"(d) : "v"(a), "v"(b))            // src0 bcast hi
#define PKM_B0(d,a,b)       asm("v_pk_mul_f32 %0, %1, %2 op_sel:[0,0] op_sel_hi:[1,0]" : "=v"(d) : "v"(a), "v"(b))            // src1 bcast lo

__global__ __launch_bounds__(TPB, 6)
void afa_fused(const float* __restrict__ in, const float* __restrict__ bias,
               const float* __restrict__ upf, const float* __restrict__ dnf,
               float* __restrict__ out)
{
    __shared__ __align__(16) float lds[LDS_FLOATS];
    float* const s_t1 = lds;    // [72][132]
    float* const s_t2 = lds;    // [64][140], aliases t1 after fusedV reads complete

    const int tid = threadIdx.x;
    const int plane = blockIdx.x;            // 4096 blocks, one 64x64 plane each

    // taps. filt[0] = filt[11] = 0 structurally -> 5-tap up phases, 10-tap down.
    // gp[k] = {2f[9-2k], 2f[10-2k]} ; fh[m] = {sqrt2*f[2m+1], sqrt2*f[2m+2]} (lrelu sqrt2 folded)
    // fdp[m] = {f[10-2m], f[9-2m]}  (W-down even/odd-tap pairs)
    v2f gp[5], fh[5], fdp[5];
#pragma unroll
    for (int k = 0; k < 5; ++k) {
        gp[k]  = (v2f){2.0f * upf[9 - 2*k], 2.0f * upf[10 - 2*k]};
        fh[k]  = (v2f){1.41421356237309515f * dnf[2*k + 1], 1.41421356237309515f * dnf[2*k + 2]};
        fdp[k] = (v2f){dnf[10 - 2*k], dnf[9 - 2*k]};
    }
    const float bv = bias[plane & 511];
    const v2f b2  = (v2f){bv, bv};
    const v2f cst = (v2f){0.6f, 0.4f};      // lrelu: 0.6x + 0.4|x| (sqrt2 folded into fh)
    const v2f z2  = (v2f){0.f, 0.f};

    // ---- zero t1 pad rows 0..3 and 68..71
    if (tid < 264) {
        *(float2*)(s_t1 + 2 * tid) = make_float2(0.f, 0.f);
        *(float2*)(s_t1 + 68 * T1S + 2 * tid) = make_float2(0.f, 0.f);
    }

    // ---- A: global load + horizontal (W) x2 upsample -> t1. 512 units = (r 0..63, cb 0..7).
    {
        const int r  = tid >> 3;
        const int cb = tid & 7;
        const float4* p4 = (const float4*)(in + (size_t)plane * (H * W) + r * W);
        float4 q0 = p4[cb == 0 ? 0 : 2 * cb - 1];
        const float4 q1 = p4[2 * cb];
        const float4 q2 = p4[2 * cb + 1];
        float4 q3 = p4[cb == 7 ? 15 : 2 * cb + 2];
        if (cb == 0) q0 = make_float4(0.f, 0.f, 0.f, 0.f);
        if (cb == 7) q3 = make_float4(0.f, 0.f, 0.f, 0.f);
        v2f wr2[6];                          // window x[8cb-2 .. 8cb+9] as 6 pairs
        wr2[0] = (v2f){q0.z, q0.w};
        wr2[1] = (v2f){q1.x, q1.y};  wr2[2] = (v2f){q1.z, q1.w};
        wr2[3] = (v2f){q2.x, q2.y};  wr2[4] = (v2f){q2.z, q2.w};
        wr2[5] = (v2f){q3.x, q3.y};
        v2f po[8];                           // po[q] = {o[2q], o[2q+1]}
#pragma unroll
        for (int q = 0; q < 8; ++q) {
            if (q & 1) { PKM_A1(po[q], wr2[q >> 1], gp[0]); }
            else       { PKM_A0(po[q], wr2[q >> 1], gp[0]); }
#pragma unroll
            for (int k = 1; k < 5; ++k) {
                if ((q + k) & 1) { PKF_ACC_A1(po[q], wr2[(q + k) >> 1], gp[k]); }
                else             { PKF_ACC_A0(po[q], wr2[(q + k) >> 1], gp[k]); }
            }
        }
        float* dst = s_t1 + (r + 4) * T1S + 16 * cb;
#pragma unroll
        for (int k = 0; k < 4; ++k)
            *(float4*)(dst + 4 * k) = make_float4(po[2*k][0], po[2*k][1], po[2*k+1][0], po[2*k+1][1]);
    }
    __syncthreads();

    // ---- fusedV: H-up + bias + lrelu + H-down in registers (packed over col-pairs).
    // 512 units = (col-pair c 0..63, group q 0..7); reads t1 rows 8q..8q+15.
    const int c = tid & 63;
    const int q = tid >> 6;                  // wave-uniform
    v2f accp[8] = {z2, z2, z2, z2, z2, z2, z2, z2};
    {
        v2f cc[16];
#pragma unroll
        for (int t = 0; t < 16; ++t)
            cc[t] = *(const v2f*)(s_t1 + (8 * q + t) * T1S + 2 * c);
        const bool mlo = (q == 0);           // j = s-4 < 0      for t < 2
        const bool mhi = (q == 7);           // j = 108+s >= 128 for t >= 10
#pragma unroll
        for (int t = 0; t < 12; ++t) {
            // ir rows s=2t (taps gp.x) and s=2t+1 (taps gp.y), window cc[t..t+4]
            v2f ta, tb;
            PKF_NEW_B0(ta, cc[t], gp[0], b2);
            PKF_NEW_B1(tb, cc[t], gp[0], b2);
#pragma unroll
            for (int k = 1; k < 5; ++k) {
                PKF_ACC_B0(ta, cc[t + k], gp[k]);
                PKF_ACC_B1(tb, cc[t + k], gp[k]);
            }
            if (mlo && t < 2)   { ta = z2; tb = z2; }
            if (mhi && t >= 10) { ta = z2; tb = z2; }
            // lrelu (unscaled): r = 0.6x + 0.4|x|
            v2f ra, aa, rb, ab;
            PKM_B0(ra, ta, cst);
            aa[0] = __builtin_fabsf(ta[0]); aa[1] = __builtin_fabsf(ta[1]);
            PKF_ACC_B1(ra, aa, cst);
            PKM_B0(rb, tb, cst);
            ab[0] = __builtin_fabsf(tb[0]); ab[1] = __builtin_fabsf(tb[1]);
            PKF_ACC_B1(rb, ab, cst);
            // H-down accumulate: t2 row 8q+p <- ir rows s in [2p, 2p+9]; even s -> fh.y, odd s -> fh.x
#pragma unroll
            for (int p = 0; p < 8; ++p) {
                if (p <= t && t <= p + 4) {
                    const int m = 4 - (t - p);
                    PKF_ACC_B1(accp[p], ra, fh[m]);
                    PKF_ACC_B0(accp[p], rb, fh[m]);
                }
            }
        }
    }
    __syncthreads();   // all t1 reads done; t2 may overwrite the aliased LDS

    // ---- store acc -> t2 + halo cols
#pragma unroll
    for (int p = 0; p < 8; ++p)
        *(v2f*)(s_t2 + (8 * q + p) * T2S + T2_OFF + 2 * c) = accp[p];
    {
        const int rw = tid >> 3, cz = tid & 7;     // 64 rows x 8 halo words
        s_t2[rw * T2S + (cz < 4 ? cz : 128 + cz)] = 0.f;
    }
    __syncthreads();

    // ---- Wdown: horizontal (W) /2 downsample -> global. 1024 units, 2 per thread.
    // o[p] = hadd( sum_m W[p+m] * fdp[m] ), W[j] = t2 col-pair {2j, 2j+1} of the unit window.
#pragma unroll
    for (int s_ = 0; s_ < 2; ++s_) {
        const int u = tid + 512 * s_;
        const int oy = u >> 4, oxb = u & 15;
        const float* base = s_t2 + oy * T2S + 8 * oxb;   // float col 8oxb-4 (incl. T2_OFF)
        v2f Wp[8];
#pragma unroll
        for (int j = 0; j < 8; ++j) Wp[j] = *(const v2f*)(base + 2 * j);
        float o2[4];
#pragma unroll
        for (int p = 0; p < 4; ++p) {
            v2f acc;
            PKM_P(acc, Wp[p], fdp[0]);
#pragma unroll
            for (int m = 1; m < 5; ++m)
                PKF_ACC_P(acc, Wp[p + m], fdp[m]);
            o2[p] = acc[0] + acc[1];
        }
        float* po = out + (size_t)plane * (H * W) + oy * W + 4 * oxb;
        *(float4*)po = make_float4(o2[0], o2[1], o2[2], o2[3]);
    }
}

extern "C" void kernel_launch(void* const* d_in, const int* in_sizes, int n_in,
                              void* d_out, int out_size, void* d_ws, size_t ws_size,
                              hipStream_t stream) {
    const float* in  = (const float*)d_in[0];
    const float* bv  = (const float*)d_in[1];
    const float* upf = (const float*)d_in[2];
    const float* dnf = (const float*)d_in[3];
    float* out = (float*)d_out;
    afa_fused<<<8 * 512, TPB, 0, stream>>>(in, bv, upf, dnf, out);
}